// Round 1
// baseline (302.457 us; speedup 1.0000x reference)
//
#include <hip/hip_runtime.h>

// Problem constants
#define N_TOK 2304
#define CDIM  1280
#define NH    8
#define DH    160
#define NBH   16          // B * NH
#define NKT   36          // N_TOK / 64
#define SCALE 0.07905694150420949f   // 1/sqrt(160)
#define LOG2E 1.4426950408889634f

typedef __attribute__((ext_vector_type(8))) short bf16x8;
typedef __attribute__((ext_vector_type(4))) float f32x4;

#define MFMA16(a, b, c) __builtin_amdgcn_mfma_f32_16x16x32_bf16((a), (b), (c), 0, 0, 0)

static __device__ __forceinline__ unsigned short f2bf(float f) {
  // round-to-nearest-even f32 -> bf16 (finite inputs only)
  unsigned int u = __builtin_bit_cast(unsigned int, f);
  u += 0x7fffu + ((u >> 16) & 1u);
  return (unsigned short)(u >> 16);
}

// ---------------- prep kernels ----------------

// cast hidden_states f32 -> bf16, 8 elems/thread
__global__ void cast_x_kernel(const float* __restrict__ x, unsigned short* __restrict__ xbf) {
  int i = blockIdx.x * 256 + threadIdx.x;          // 737280 threads total
  const float4* p = (const float4*)x + (size_t)i * 2;
  float4 a = p[0], b = p[1];
  union { unsigned short u[8]; uint4 v; } pk;
  pk.u[0] = f2bf(a.x); pk.u[1] = f2bf(a.y); pk.u[2] = f2bf(a.z); pk.u[3] = f2bf(a.w);
  pk.u[4] = f2bf(b.x); pk.u[5] = f2bf(b.y); pk.u[6] = f2bf(b.z); pk.u[7] = f2bf(b.w);
  ((uint4*)xbf)[i] = pk.v;
}

// Wt[w][n][k] = W_w[k][n], f32 -> bf16.  32x32 tiles through LDS.
__global__ void transpose_w_kernel(const float* __restrict__ wq, const float* __restrict__ wk,
                                   const float* __restrict__ wv, unsigned short* __restrict__ wt) {
  __shared__ float t[32][33];
  const int w = blockIdx.z;
  const float* src = (w == 0) ? wq : ((w == 1) ? wk : wv);
  const int bx = blockIdx.x * 32;   // n
  const int by = blockIdx.y * 32;   // k
  const int tx = threadIdx.x, ty = threadIdx.y;
  for (int i = 0; i < 32; i += 8)
    t[ty + i][tx] = src[(size_t)(by + ty + i) * CDIM + bx + tx];
  __syncthreads();
  for (int i = 0; i < 32; i += 8)
    wt[((size_t)w * CDIM + bx + ty + i) * CDIM + by + tx] = f2bf(t[tx][ty + i]);
}

// masks (0 or -1e4 f32) -> visibility bitmask, one u64 per (b,i,64-col block)
__global__ void mask_bits_kernel(const float* __restrict__ masks,
                                 unsigned long long* __restrict__ bits) {
  int t = blockIdx.x * 256 + threadIdx.x;
  int word = t >> 6, lane = t & 63;
  int jblk = word % NKT, bi = word / NKT;          // bi = b*N + i
  float m = masks[(size_t)bi * N_TOK + jblk * 64 + lane];
  unsigned long long vis = __ballot(m > -5000.0f);
  if (lane == 0) bits[word] = vis;
}

// ---------------- QKV projection GEMM ----------------
// Y[4608][3840] = Xbf[4608][1280] . Wt^T ; writes Q,K as [bh][n][160] bf16,
// V transposed as [bh][160][n] bf16 (so attention PV B-frags are contiguous).
__global__ __launch_bounds__(256, 3) void gemm_qkv_kernel(
    const unsigned short* __restrict__ xbf, const unsigned short* __restrict__ wt,
    unsigned short* __restrict__ qb, unsigned short* __restrict__ kb,
    unsigned short* __restrict__ vtb) {
  // stride 88 shorts = 176B: 16B-aligned rows, 2-way bank aliasing (free)
  __shared__ unsigned short Al[128][88];
  __shared__ unsigned short Bl[128][88];
  const int tid = threadIdx.x;
  const int lane = tid & 63, wv = tid >> 6;
  const int wm = wv >> 1, wn = wv & 1;
  const int l15 = lane & 15, l4 = lane >> 4;
  const int m0 = blockIdx.x * 128, n0 = blockIdx.y * 128;
  f32x4 zero = {0.f, 0.f, 0.f, 0.f};
  f32x4 acc[4][4];
#pragma unroll
  for (int mt = 0; mt < 4; mt++)
#pragma unroll
    for (int nt = 0; nt < 4; nt++) acc[mt][nt] = zero;

  for (int kk = 0; kk < CDIM; kk += 64) {
    __syncthreads();
#pragma unroll
    for (int i = 0; i < 4; i++) {
      int idx = i * 256 + tid;
      int r = idx >> 3, c = (idx & 7) * 8;
      *(uint4*)&Al[r][c] = *(const uint4*)&xbf[(size_t)(m0 + r) * CDIM + kk + c];
      *(uint4*)&Bl[r][c] = *(const uint4*)&wt[(size_t)(n0 + r) * CDIM + kk + c];
    }
    __syncthreads();
#pragma unroll
    for (int ks = 0; ks < 2; ks++) {
      bf16x8 af[4], bfr[4];
#pragma unroll
      for (int mt = 0; mt < 4; mt++)
        af[mt] = *(const bf16x8*)&Al[wm * 64 + mt * 16 + l15][ks * 32 + l4 * 8];
#pragma unroll
      for (int nt = 0; nt < 4; nt++)
        bfr[nt] = *(const bf16x8*)&Bl[wn * 64 + nt * 16 + l15][ks * 32 + l4 * 8];
#pragma unroll
      for (int mt = 0; mt < 4; mt++)
#pragma unroll
        for (int nt = 0; nt < 4; nt++)
          acc[mt][nt] = MFMA16(af[mt], bfr[nt], acc[mt][nt]);
    }
  }

  const int w_idx = n0 / CDIM;                 // 0=Q 1=K 2=V, block-uniform
  const int cbase = n0 - w_idx * CDIM + wn * 64;
#pragma unroll
  for (int mt = 0; mt < 4; mt++) {
    const int mg = m0 + wm * 64 + mt * 16 + l4 * 4;  // token row (r=0)
    const int b = mg / N_TOK;
    const int tok = mg - b * N_TOK;
#pragma unroll
    for (int nt = 0; nt < 4; nt++) {
      const int cw = cbase + nt * 16 + l15;
      const int h = cw / DH, d = cw - h * DH;
      const size_t bh = (size_t)(b * NH + h);
      if (w_idx == 2) {
        // V^T: pack 4 consecutive tokens into one 8B store
        union { unsigned short u[4]; unsigned long long v; } pk;
        pk.u[0] = f2bf(acc[mt][nt][0]); pk.u[1] = f2bf(acc[mt][nt][1]);
        pk.u[2] = f2bf(acc[mt][nt][2]); pk.u[3] = f2bf(acc[mt][nt][3]);
        *(unsigned long long*)&vtb[(bh * DH + d) * N_TOK + tok] = pk.v;
      } else {
        unsigned short* dst = (w_idx == 0) ? qb : kb;
#pragma unroll
        for (int r = 0; r < 4; r++)
          dst[(bh * N_TOK + tok + r) * DH + d] = f2bf(acc[mt][nt][r]);
      }
    }
  }
}

// ---------------- fused masked flash attention ----------------
// grid (36 q-tiles, 16 bh), 4 waves x 16 q-rows, KBLK=64, online softmax.
__global__ __launch_bounds__(256, 2) void attn_kernel(
    const unsigned short* __restrict__ qb, const unsigned short* __restrict__ kb,
    const unsigned short* __restrict__ vtb, const unsigned long long* __restrict__ bits,
    float* __restrict__ out) {
  __shared__ unsigned short Kl[64][168];   // 336B rows: 16B-aligned, 2-way banks
  __shared__ unsigned short Vl[160][88];   // 176B rows
  __shared__ unsigned short Pl[4][16][80]; // per-wave P tile, 160B rows
  const int tid = threadIdx.x;
  const int lane = tid & 63, wv = tid >> 6;
  const int l15 = lane & 15, l4 = lane >> 4;
  const int bh = blockIdx.y, b = bh >> 3, h = bh & 7;
  const int q0 = blockIdx.x * 64 + wv * 16;
  const unsigned short* kbase = kb + (size_t)bh * N_TOK * DH;
  const unsigned short* vbase = vtb + (size_t)bh * DH * N_TOK;

  bf16x8 qf[5];
  {
    const unsigned short* qrow = qb + ((size_t)bh * N_TOK + q0 + l15) * DH + l4 * 8;
#pragma unroll
    for (int ks = 0; ks < 5; ks++) qf[ks] = *(const bf16x8*)&qrow[ks * 32];
  }
  float run_m[4], run_l[4];
#pragma unroll
  for (int r = 0; r < 4; r++) { run_m[r] = -3.0e38f; run_l[r] = 0.0f; }
  f32x4 zero = {0.f, 0.f, 0.f, 0.f};
  f32x4 o[10];
#pragma unroll
  for (int dt = 0; dt < 10; dt++) o[dt] = zero;

  for (int kt = 0; kt < NKT; kt++) {
    __syncthreads();   // previous iteration's LDS reads done
#pragma unroll
    for (int i = 0; i < 5; i++) {
      int idx = i * 256 + tid;                     // 1280 16B chunks each
      int r = idx / 20, c = (idx - r * 20) * 8;
      *(uint4*)&Kl[r][c] = *(const uint4*)&kbase[(size_t)(kt * 64 + r) * DH + c];
      int r2 = idx >> 3, c2 = (idx & 7) * 8;
      *(uint4*)&Vl[r2][c2] = *(const uint4*)&vbase[(size_t)r2 * N_TOK + kt * 64 + c2];
    }
    __syncthreads();

    // S = Q K^T  (per wave: 16 rows x 64 cols)
    f32x4 s[4];
#pragma unroll
    for (int ct = 0; ct < 4; ct++) s[ct] = zero;
#pragma unroll
    for (int ks = 0; ks < 5; ks++) {
#pragma unroll
      for (int ct = 0; ct < 4; ct++) {
        bf16x8 kf = *(const bf16x8*)&Kl[ct * 16 + l15][ks * 32 + l4 * 8];
        s[ct] = MFMA16(qf[ks], kf, s[ct]);
      }
    }

    // isolation mask from bitmask (L2-resident)
    unsigned long long mw[4];
#pragma unroll
    for (int r = 0; r < 4; r++)
      mw[r] = bits[((size_t)b * N_TOK + q0 + l4 * 4 + r) * NKT + kt];

    float pm[4];
#pragma unroll
    for (int r = 0; r < 4; r++) pm[r] = -3.0e38f;
#pragma unroll
    for (int ct = 0; ct < 4; ct++)
#pragma unroll
      for (int r = 0; r < 4; r++) {
        float v = s[ct][r] * SCALE;
        if (!((mw[r] >> (ct * 16 + l15)) & 1ull)) v -= 10000.0f;
        s[ct][r] = v;
        pm[r] = fmaxf(pm[r], v);
      }
    // row max across the 16 lanes holding this row's columns
#pragma unroll
    for (int r = 0; r < 4; r++) {
      pm[r] = fmaxf(pm[r], __shfl_xor(pm[r], 1));
      pm[r] = fmaxf(pm[r], __shfl_xor(pm[r], 2));
      pm[r] = fmaxf(pm[r], __shfl_xor(pm[r], 4));
      pm[r] = fmaxf(pm[r], __shfl_xor(pm[r], 8));
    }
    float fct[4], rs[4];
#pragma unroll
    for (int r = 0; r < 4; r++) {
      float nm = fmaxf(run_m[r], pm[r]);
      fct[r] = exp2f((run_m[r] - nm) * LOG2E);
      run_m[r] = nm;
      rs[r] = 0.0f;
    }
#pragma unroll
    for (int ct = 0; ct < 4; ct++)
#pragma unroll
      for (int r = 0; r < 4; r++) {
        float p = exp2f((s[ct][r] - run_m[r]) * LOG2E);
        s[ct][r] = p;
        rs[r] += p;
      }
#pragma unroll
    for (int r = 0; r < 4; r++) {
      rs[r] += __shfl_xor(rs[r], 1);
      rs[r] += __shfl_xor(rs[r], 2);
      rs[r] += __shfl_xor(rs[r], 4);
      rs[r] += __shfl_xor(rs[r], 8);
      run_l[r] = run_l[r] * fct[r] + rs[r];
    }
#pragma unroll
    for (int dt = 0; dt < 10; dt++)
#pragma unroll
      for (int r = 0; r < 4; r++) o[dt][r] *= fct[r];

    // P (C-layout) -> LDS -> A-layout fragments
#pragma unroll
    for (int ct = 0; ct < 4; ct++)
#pragma unroll
      for (int r = 0; r < 4; r++)
        Pl[wv][l4 * 4 + r][ct * 16 + l15] = f2bf(s[ct][r]);
    __syncthreads();   // cross-lane visibility of Pl (also keeps waves in step)

#pragma unroll
    for (int ks2 = 0; ks2 < 2; ks2++) {
      bf16x8 pf = *(const bf16x8*)&Pl[wv][l15][ks2 * 32 + l4 * 8];
#pragma unroll
      for (int dt = 0; dt < 10; dt++) {
        bf16x8 vf = *(const bf16x8*)&Vl[dt * 16 + l15][ks2 * 32 + l4 * 8];
        o[dt] = MFMA16(pf, vf, o[dt]);
      }
    }
  }

  float inv[4];
#pragma unroll
  for (int r = 0; r < 4; r++) inv[r] = 1.0f / run_l[r];
#pragma unroll
  for (int dt = 0; dt < 10; dt++)
#pragma unroll
    for (int r = 0; r < 4; r++)
      out[(size_t)b * N_TOK * CDIM + (size_t)(q0 + l4 * 4 + r) * CDIM +
          h * DH + dt * 16 + l15] = o[dt][r] * inv[r];
}

// ---------------- launcher ----------------
extern "C" void kernel_launch(void* const* d_in, const int* in_sizes, int n_in,
                              void* d_out, int out_size, void* d_ws, size_t ws_size,
                              hipStream_t stream) {
  const float* hs    = (const float*)d_in[0];
  const float* wq    = (const float*)d_in[1];
  const float* wk    = (const float*)d_in[2];
  const float* wvw   = (const float*)d_in[3];
  const float* masks = (const float*)d_in[4];
  float* out = (float*)d_out;

  char* ws = (char*)d_ws;
  unsigned short* xbf = (unsigned short*)(ws);                    // 11,796,480 B
  unsigned short* wt  = (unsigned short*)(ws + 11796480);         //  9,830,400 B
  unsigned short* qb  = (unsigned short*)(ws + 21626880);         // 11,796,480 B
  unsigned short* kb  = (unsigned short*)(ws + 33423360);         // 11,796,480 B
  unsigned short* vtb = (unsigned short*)(ws + 45219840);         // 11,796,480 B
  unsigned long long* bits = (unsigned long long*)(ws + 57016320);//  1,327,104 B
  // total workspace: 58,343,424 B

  cast_x_kernel<<<2880, 256, 0, stream>>>(hs, xbf);
  transpose_w_kernel<<<dim3(40, 40, 3), dim3(32, 8), 0, stream>>>(wq, wk, wvw, wt);
  mask_bits_kernel<<<41472, 256, 0, stream>>>(masks, bits);
  gemm_qkv_kernel<<<dim3(36, 30), 256, 0, stream>>>(xbf, wt, qb, kb, vtb);
  attn_kernel<<<dim3(36, 16), 256, 0, stream>>>(qb, kb, vtb, bits, out);
}

// Round 3
// 261.590 us; speedup vs baseline: 1.1562x; 1.1562x over previous
//
#include <hip/hip_runtime.h>

// Problem constants
#define N_TOK 2304
#define CDIM  1280
#define NH    8
#define DH    160
#define NKT   36          // N_TOK / 64  (bitmask words per row)
#define SCALE 0.07905694150420949f   // 1/sqrt(160)
#define LOG2E 1.4426950408889634f

typedef __attribute__((ext_vector_type(8))) short bf16x8;
typedef __attribute__((ext_vector_type(4))) float f32x4;
typedef __attribute__((ext_vector_type(16))) float f32x16;

#define MFMA16(a, b, c) __builtin_amdgcn_mfma_f32_16x16x32_bf16((a), (b), (c), 0, 0, 0)
#define MFMA32(a, b, c) __builtin_amdgcn_mfma_f32_32x32x16_bf16((a), (b), (c), 0, 0, 0)

static __device__ __forceinline__ unsigned short f2bf(float f) {
  // round-to-nearest-even f32 -> bf16 (finite inputs only)
  unsigned int u = __builtin_bit_cast(unsigned int, f);
  u += 0x7fffu + ((u >> 16) & 1u);
  return (unsigned short)(u >> 16);
}

static __device__ __forceinline__ float fexp2(float x) {
#if __has_builtin(__builtin_amdgcn_exp2f)
  return __builtin_amdgcn_exp2f(x);
#else
  return exp2f(x);
#endif
}

// global -> LDS direct DMA, 16B per lane. LDS dest is wave-uniform base + lane*16.
// Low 32 bits of a generic LDS address are the LDS byte offset on gfx9+.
static __device__ __forceinline__ void gload_lds16(const void* g, void* l) {
  const __attribute__((address_space(1))) unsigned int* gp =
      (const __attribute__((address_space(1))) unsigned int*)(unsigned long long)(uintptr_t)g;
  __attribute__((address_space(3))) unsigned int* lp =
      (__attribute__((address_space(3))) unsigned int*)(unsigned int)(uintptr_t)l;
  __builtin_amdgcn_global_load_lds(gp, lp, 16, 0, 0);
}

// ---------------- prep kernels ----------------

// cast hidden_states f32 -> bf16, 8 elems/thread
__global__ void cast_x_kernel(const float* __restrict__ x, unsigned short* __restrict__ xbf) {
  int i = blockIdx.x * 256 + threadIdx.x;
  const float4* p = (const float4*)x + (size_t)i * 2;
  float4 a = p[0], b = p[1];
  union { unsigned short u[8]; uint4 v; } pk;
  pk.u[0] = f2bf(a.x); pk.u[1] = f2bf(a.y); pk.u[2] = f2bf(a.z); pk.u[3] = f2bf(a.w);
  pk.u[4] = f2bf(b.x); pk.u[5] = f2bf(b.y); pk.u[6] = f2bf(b.z); pk.u[7] = f2bf(b.w);
  ((uint4*)xbf)[i] = pk.v;
}

// Wt[w][n][k] = W_w[k][n], f32 -> bf16.  32x32 tiles through LDS.
__global__ void transpose_w_kernel(const float* __restrict__ wq, const float* __restrict__ wk,
                                   const float* __restrict__ wv, unsigned short* __restrict__ wt) {
  __shared__ float t[32][33];
  const int w = blockIdx.z;
  const float* src = (w == 0) ? wq : ((w == 1) ? wk : wv);
  const int bx = blockIdx.x * 32;   // n
  const int by = blockIdx.y * 32;   // k
  const int tx = threadIdx.x, ty = threadIdx.y;
  for (int i = 0; i < 32; i += 8)
    t[ty + i][tx] = src[(size_t)(by + ty + i) * CDIM + bx + tx];
  __syncthreads();
  for (int i = 0; i < 32; i += 8)
    wt[((size_t)w * CDIM + bx + ty + i) * CDIM + by + tx] = f2bf(t[tx][ty + i]);
}

// masks (0 or -1e4 f32) -> visibility bitmask, one u64 per (b,i,64-col block)
__global__ void mask_bits_kernel(const float* __restrict__ masks,
                                 unsigned long long* __restrict__ bits) {
  int t = blockIdx.x * 256 + threadIdx.x;
  int word = t >> 6, lane = t & 63;
  int jblk = word % NKT, bi = word / NKT;          // bi = b*N + i
  float m = masks[(size_t)bi * N_TOK + jblk * 64 + lane];
  unsigned long long vis = __ballot(m > -5000.0f);
  if (lane == 0) bits[word] = vis;
}

// ---------------- QKV projection GEMM ----------------
// Q pre-scaled by SCALE*LOG2E; K as [bh][n][160]; V transposed [bh][160][n].
__global__ __launch_bounds__(256, 3) void gemm_qkv_kernel(
    const unsigned short* __restrict__ xbf, const unsigned short* __restrict__ wt,
    unsigned short* __restrict__ qb, unsigned short* __restrict__ kb,
    unsigned short* __restrict__ vtb) {
  __shared__ unsigned short Al[128][88];
  __shared__ unsigned short Bl[128][88];
  const int tid = threadIdx.x;
  const int lane = tid & 63, wv = tid >> 6;
  const int wm = wv >> 1, wn = wv & 1;
  const int l15 = lane & 15, l4 = lane >> 4;
  const int m0 = blockIdx.x * 128, n0 = blockIdx.y * 128;
  f32x4 zero = {0.f, 0.f, 0.f, 0.f};
  f32x4 acc[4][4];
#pragma unroll
  for (int mt = 0; mt < 4; mt++)
#pragma unroll
    for (int nt = 0; nt < 4; nt++) acc[mt][nt] = zero;

  for (int kk = 0; kk < CDIM; kk += 64) {
    __syncthreads();
#pragma unroll
    for (int i = 0; i < 4; i++) {
      int idx = i * 256 + tid;
      int r = idx >> 3, c = (idx & 7) * 8;
      *(uint4*)&Al[r][c] = *(const uint4*)&xbf[(size_t)(m0 + r) * CDIM + kk + c];
      *(uint4*)&Bl[r][c] = *(const uint4*)&wt[(size_t)(n0 + r) * CDIM + kk + c];
    }
    __syncthreads();
#pragma unroll
    for (int ks = 0; ks < 2; ks++) {
      bf16x8 af[4], bfr[4];
#pragma unroll
      for (int mt = 0; mt < 4; mt++)
        af[mt] = *(const bf16x8*)&Al[wm * 64 + mt * 16 + l15][ks * 32 + l4 * 8];
#pragma unroll
      for (int nt = 0; nt < 4; nt++)
        bfr[nt] = *(const bf16x8*)&Bl[wn * 64 + nt * 16 + l15][ks * 32 + l4 * 8];
#pragma unroll
      for (int mt = 0; mt < 4; mt++)
#pragma unroll
        for (int nt = 0; nt < 4; nt++)
          acc[mt][nt] = MFMA16(af[mt], bfr[nt], acc[mt][nt]);
    }
  }

  const int w_idx = n0 / CDIM;                 // 0=Q 1=K 2=V, block-uniform
  if (w_idx == 0) {
    const float qsc = (float)(0.07905694150420949 * 1.4426950408889634);
#pragma unroll
    for (int mt = 0; mt < 4; mt++)
#pragma unroll
      for (int nt = 0; nt < 4; nt++) acc[mt][nt] *= qsc;
  }
  const int cbase = n0 - w_idx * CDIM + wn * 64;
#pragma unroll
  for (int mt = 0; mt < 4; mt++) {
    const int mg = m0 + wm * 64 + mt * 16 + l4 * 4;  // token row (r=0)
    const int b = mg / N_TOK;
    const int tok = mg - b * N_TOK;
#pragma unroll
    for (int nt = 0; nt < 4; nt++) {
      const int cw = cbase + nt * 16 + l15;
      const int h = cw / DH, d = cw - h * DH;
      const size_t bh = (size_t)(b * NH + h);
      if (w_idx == 2) {
        union { unsigned short u[4]; unsigned long long v; } pk;
        pk.u[0] = f2bf(acc[mt][nt][0]); pk.u[1] = f2bf(acc[mt][nt][1]);
        pk.u[2] = f2bf(acc[mt][nt][2]); pk.u[3] = f2bf(acc[mt][nt][3]);
        *(unsigned long long*)&vtb[(bh * DH + d) * N_TOK + tok] = pk.v;
      } else {
        unsigned short* dst = (w_idx == 0) ? qb : kb;
#pragma unroll
        for (int r = 0; r < 4; r++)
          dst[(bh * N_TOK + tok + r) * DH + d] = f2bf(acc[mt][nt][r]);
      }
    }
  }
}

// ---------------- fused masked flash attention v2.1 ----------------
// 2 waves x 32 q-rows, 32x32x16 MFMA, swapped QK^T (lane-local softmax),
// KVBLK=32 double-buffered via global_load_lds with ((row>>1)&3) XOR swizzle
// (both sides -> conflict-free b128 reads), in-register P transpose via
// v_permlane32_swap_b32, one barrier/iter.  LDS 40960 B -> 4 blocks/CU.
__global__ __launch_bounds__(128) void attn2_kernel(
    const unsigned short* __restrict__ qb, const unsigned short* __restrict__ kb,
    const unsigned short* __restrict__ vtb, const unsigned int* __restrict__ bits32,
    float* __restrict__ out) {
  // buf b: K tile [32][160] at b*20480, V tile [160][32] at b*20480+10240.
  // Epilogue reuses smem as swizzled Ob[64][160] f32 (40960 B).
  __shared__ __align__(16) char smem[40960];
  const int tid = threadIdx.x;
  const int lane = tid & 63, wv = tid >> 6;
  const int l31 = lane & 31, h = lane >> 5;
  const int id = blockIdx.x;
  const int rem = (id & 7) * 72 + (id >> 3);   // XCD-chunked remap (576 = 8*72)
  const int bh = rem / 36, xt = rem - (rem / 36) * 36;
  const int b = bh >> 3;
  const int q0 = xt * 64;
  const int wq = q0 + wv * 32 + l31;           // this lane's q token

  const unsigned short* kbase = kb + (size_t)bh * N_TOK * DH;
  const unsigned short* vbase = vtb + (size_t)bh * DH * N_TOK;
  const unsigned int* bptr = bits32 + ((size_t)b * N_TOK + wq) * 72;

  // Q fragments (already scaled by SCALE*LOG2E): lane holds q=wq, dims ks*16+h*8..+7
  bf16x8 qf[10];
  {
    const unsigned short* qrow = qb + ((size_t)bh * N_TOK + wq) * DH + h * 8;
#pragma unroll
    for (int ks = 0; ks < 10; ks++) qf[ks] = *(const bf16x8*)&qrow[ks * 16];
  }

  auto do_stage = [&](int t) {
    char* dst = smem + (t & 1) * 20480;
    if (wv == 0) {
      // K tile: rows = keys t*32..+31, 320B each, contiguous region
      const char* src0 = (const char*)kbase + (size_t)t * 32 * 320;
#pragma unroll
      for (int i = 0; i < 10; i++) {
        int c = i * 64 + lane;
        int r = c / 20, s = c - r * 20;
        int scb = (s * 16) ^ (((r >> 1) & 3) << 4);   // pre-swizzled source
        gload_lds16(src0 + (size_t)r * 320 + scb, dst + i * 1024);
      }
    } else {
      // V tile: 160 rows x 64B (row stride 4608B in global)
      const char* src0 = (const char*)vbase + (size_t)t * 64;
      char* dstv = dst + 10240;
#pragma unroll
      for (int i = 0; i < 10; i++) {
        int c = i * 64 + lane;
        int r = c >> 2, s = c & 3;
        int scb = (s * 16) ^ (((r >> 1) & 3) << 4);
        gload_lds16(src0 + (size_t)r * 4608 + scb, dstv + i * 1024);
      }
    }
  };

  const f32x16 zz = {0.f,0.f,0.f,0.f,0.f,0.f,0.f,0.f,0.f,0.f,0.f,0.f,0.f,0.f,0.f,0.f};
  f32x16 o[5];
#pragma unroll
  for (int dt = 0; dt < 5; dt++) o[dt] = zz;
  float run_m = -3.0e38f, run_l = 0.0f;

  do_stage(0);

  for (int kt = 0; kt < 72; kt++) {
    __syncthreads();                 // drains DMA for tile kt; guards buffer reuse
    if (kt + 1 < 72) do_stage(kt + 1);   // flies under this iteration's compute
    const char* kl = smem + (kt & 1) * 20480;
    const char* vl = kl + 10240;

    // S^T[key][q] = K . Q^T : lane holds 16 keys for q = wq
    f32x16 s = zz;
#pragma unroll
    for (int ks = 0; ks < 10; ks++) {
      int cb = ks * 32 + h * 16;
      int scb = cb ^ (((l31 >> 1) & 3) << 4);
      bf16x8 kf = *(const bf16x8*)(kl + l31 * 320 + scb);
      s = MFMA32(kf, qf[ks], s);
    }

    unsigned mw = bptr[kt];

    float pm = s[0];
#pragma unroll
    for (int r = 1; r < 16; r++) pm = fmaxf(pm, s[r]);
    pm = fmaxf(pm, __shfl_xor(pm, 32));

    // defer-max (T13): skip O-rescale unless max grew by > 8 (log2 units)
    if (!__all(pm - run_m <= 8.0f)) {
      float nm = fmaxf(run_m, pm);
      float f = fexp2(run_m - nm);
      run_m = nm;
      run_l *= f;
#pragma unroll
      for (int dt = 0; dt < 5; dt++) o[dt] *= f;
    }

    float rs = 0.0f;
    unsigned pw[8];
#pragma unroll
    for (int i = 0; i < 8; i++) {
      int k0 = ((2 * i) & 3) + 8 * (i >> 1) + 4 * h;   // key of reg 2i
      float p0 = fexp2(s[2 * i] - run_m);
      float p1 = fexp2(s[2 * i + 1] - run_m);
      p0 = ((mw >> k0) & 1u) ? p0 : 0.0f;              // mask by zeroing P
      p1 = ((mw >> (k0 + 1)) & 1u) ? p1 : 0.0f;
      rs += p0 + p1;
      unsigned w;
      asm("v_cvt_pk_bf16_f32 %0, %1, %2" : "=v"(w) : "v"(p0), "v"(p1));
      pw[i] = w;
    }
    rs += __shfl_xor(rs, 32);
    run_l += rs;

    // P-frag assembly: swap(pw[0],pw[2]) -> (w0,w2), swap(pw[1],pw[3]) -> (w1,w3)
    // (lane (l31,h) needs keys slice+8h+0..7 at column q; derivation per key(r,h))
    {
      unsigned a1 = pw[0], b1 = pw[2];
      asm("v_permlane32_swap_b32 %0, %1" : "+v"(a1), "+v"(b1));
      unsigned a2 = pw[1], b2 = pw[3];
      asm("v_permlane32_swap_b32 %0, %1" : "+v"(a2), "+v"(b2));
      union { unsigned w[4]; bf16x8 v; } u;
      u.w[0] = a1; u.w[1] = a2; u.w[2] = b1; u.w[3] = b2;
#pragma unroll
      for (int dt = 0; dt < 5; dt++) {
        int row = dt * 32 + l31;
        int scb = (h * 16) ^ (((row >> 1) & 3) << 4);
        bf16x8 vf = *(const bf16x8*)(vl + row * 64 + scb);
        o[dt] = MFMA32(vf, u.v, o[dt]);
      }
    }
    {
      unsigned a1 = pw[4], b1 = pw[6];
      asm("v_permlane32_swap_b32 %0, %1" : "+v"(a1), "+v"(b1));
      unsigned a2 = pw[5], b2 = pw[7];
      asm("v_permlane32_swap_b32 %0, %1" : "+v"(a2), "+v"(b2));
      union { unsigned w[4]; bf16x8 v; } u;
      u.w[0] = a1; u.w[1] = a2; u.w[2] = b1; u.w[3] = b2;
#pragma unroll
      for (int dt = 0; dt < 5; dt++) {
        int row = dt * 32 + l31;
        int scb = (32 + h * 16) ^ (((row >> 1) & 3) << 4);
        bf16x8 vf = *(const bf16x8*)(vl + row * 64 + scb);
        o[dt] = MFMA32(vf, u.v, o[dt]);
      }
    }
  }

  float invl = 1.0f / run_l;
  __syncthreads();                   // all compute done before Ob overwrites buffers
  // Ob: logical [64][160] f32, byte = q*640 + (d*4 ^ ((q&7)<<4))  (conflict-free)
#pragma unroll
  for (int dt = 0; dt < 5; dt++)
#pragma unroll
    for (int rr = 0; rr < 4; rr++) {
      float4 t;
      t.x = o[dt][4 * rr + 0] * invl;
      t.y = o[dt][4 * rr + 1] * invl;
      t.z = o[dt][4 * rr + 2] * invl;
      t.w = o[dt][4 * rr + 3] * invl;
      int q = wv * 32 + l31;
      int d0 = dt * 32 + 8 * rr + 4 * h;
      *(float4*)(smem + q * 640 + ((d0 * 4) ^ ((q & 7) << 4))) = t;
    }
  __syncthreads();
  float* outp = out + (size_t)b * N_TOK * CDIM + (size_t)q0 * CDIM + (bh & 7) * DH;
  for (int c = tid; c < 2560; c += 128) {
    int q = c / 40, f = c - (c / 40) * 40;
    float4 t = *(const float4*)(smem + q * 640 + ((f * 16) ^ ((q & 7) << 4)));
    *(float4*)&outp[(size_t)q * CDIM + f * 4] = t;
  }
}

// ---------------- launcher ----------------
extern "C" void kernel_launch(void* const* d_in, const int* in_sizes, int n_in,
                              void* d_out, int out_size, void* d_ws, size_t ws_size,
                              hipStream_t stream) {
  const float* hs    = (const float*)d_in[0];
  const float* wq    = (const float*)d_in[1];
  const float* wk    = (const float*)d_in[2];
  const float* wvw   = (const float*)d_in[3];
  const float* masks = (const float*)d_in[4];
  float* out = (float*)d_out;

  char* ws = (char*)d_ws;
  unsigned short* xbf = (unsigned short*)(ws);                    // 11,796,480 B
  unsigned short* wt  = (unsigned short*)(ws + 11796480);         //  9,830,400 B
  unsigned short* qb  = (unsigned short*)(ws + 21626880);         // 11,796,480 B
  unsigned short* kb  = (unsigned short*)(ws + 33423360);         // 11,796,480 B
  unsigned short* vtb = (unsigned short*)(ws + 45219840);         // 11,796,480 B
  unsigned long long* bits = (unsigned long long*)(ws + 57016320);//  1,327,104 B

  cast_x_kernel<<<2880, 256, 0, stream>>>(hs, xbf);
  transpose_w_kernel<<<dim3(40, 40, 3), dim3(32, 8), 0, stream>>>(wq, wk, wvw, wt);
  mask_bits_kernel<<<41472, 256, 0, stream>>>(masks, bits);
  gemm_qkv_kernel<<<dim3(36, 30), 256, 0, stream>>>(xbf, wt, qb, kb, vtb);
  attn2_kernel<<<576, 128, 0, stream>>>(qb, kb, vtb, (const unsigned int*)bits, out);
}